// Round 15
// baseline (275.046 us; speedup 1.0000x reference)
//
#include <hip/hip_runtime.h>
#include <hip/hip_bf16.h>
#include <math.h>
#include <type_traits>

#define LSEQ 8192
#define BATCH 4
#define M_TOK (BATCH * LSEQ)

typedef __attribute__((ext_vector_type(8))) short bf16x8;   // 8 bf16 = 4 VGPR
typedef __attribute__((ext_vector_type(4))) float f32x4;
typedef __attribute__((ext_vector_type(16))) float f32x16;

// ---------------------------------------------------------------- helpers
__device__ __forceinline__ float siluf(float x) {
  return x / (1.f + __expf(-x));
}

__device__ __forceinline__ float bf2f(uint u16) {
  union { float f; uint u; } c;
  c.u = u16 << 16;
  return c.f;
}

__device__ __forceinline__ uint cvtpk_bf16(float lo, float hi) {
  uint r;
  asm volatile("v_cvt_pk_bf16_f32 %0, %1, %2" : "=v"(r) : "v"(lo), "v"(hi));
  return r;
}

// swaps hi 32 lanes of a with lo 32 lanes of b
__device__ __forceinline__ void perm32swap(uint& a, uint& b) {
  asm volatile("v_permlane32_swap_b32 %0, %1" : "+v"(a), "+v"(b));
}

// async global->LDS, 16B per lane; LDS dest = wave-uniform base + lane*16
__device__ __forceinline__ void gload16(const ushort* g, short* l) {
  __builtin_amdgcn_global_load_lds(
      (const __attribute__((address_space(1))) void*)g,
      (__attribute__((address_space(3))) void*)l, 16, 0, 0);
}

// ---------------------------------------------------------------- setup
#define NW1 (512 * 576)
#define NW3 (512 * 512)
#define NW2 (1536 * 512)
#define NW4 (384 * 192)
#define NTAB (8192 * 32)

__global__ __launch_bounds__(256) void setup_kernel(
    const float* __restrict__ inst_w, const float* __restrict__ outp_w,
    const float* __restrict__ qkv_w, const float* __restrict__ reg_w,
    const float* __restrict__ reg_b, const float* __restrict__ br_w,
    const float* __restrict__ br_b, const float* __restrict__ mem_w,
    const float* __restrict__ mem_b, __hip_bfloat16* __restrict__ w16,
    float2* __restrict__ tab) {
  int i = blockIdx.x * 256 + threadIdx.x;
  if (i < NW1) {
    w16[i] = __float2bfloat16(inst_w[i]);
    return;
  }
  i -= NW1;
  if (i < NW3) {
    w16[NW1 + i] = __float2bfloat16(outp_w[i]);
    return;
  }
  i -= NW3;
  if (i < NW2) {
    // qkv row permutation: out row n' = which*512 + h*64 + d
    // from src row n = h*192 + d*3 + which -> qkvb planes [Q|K|V]
    int np = i / 512, k = i % 512;
    int which = np >> 9, rem = np & 511;
    int h = rem >> 6, d = rem & 63;
    int n = h * 192 + d * 3 + which;
    w16[NW1 + NW3 + i] = __float2bfloat16(qkv_w[n * 512 + k]);
    return;
  }
  i -= NW2;
  if (i < NW4) {
    // Wcat[384][192]: F cols [0]=1(bias),[1..64]=reg,[65..128]=mem,[129..160]=br
    int o = i / 192, c = i % 192;
    float v = 0.f;
    if (o < 128) {
      if (c == 0) v = reg_b[o];
      else if (c <= 64) v = reg_w[o * 64 + (c - 1)];
    } else if (o < 256) {
      int oo = o - 128;
      if (c == 0) v = br_b[oo];
      else if (c >= 129 && c <= 160) v = br_w[oo * 32 + (c - 129)];
    } else {
      int oo = o - 256;
      if (c == 0) v = mem_b[oo];
      else if (c >= 65 && c <= 128) v = mem_w[oo * 64 + (c - 65)];
    }
    w16[NW1 + NW3 + NW2 + i] = __float2bfloat16(v);
    return;
  }
  i -= NW4;
  if (i < NTAB) {
    int pos = i >> 5, p = i & 31;
    float inv = expf(-(float)p * 0.28782313662f);  // ln(10000)/32
    float sn, cs;
    sincosf((float)pos * inv, &sn, &cs);
    tab[i] = make_float2(cs, sn);
  }
}

// ---------------------------------------------------------------- prep
__global__ __launch_bounds__(256) void prep_kernel(
    const int* __restrict__ x, const float* __restrict__ emb,
    __hip_bfloat16* __restrict__ cat, __hip_bfloat16* __restrict__ Fb) {
  int gid = blockIdx.x * 256 + threadIdx.x;
  int t = gid / 48;
  int g = gid % 48;
  if (t >= M_TOK) return;
  const int* xr = x + (size_t)t * 161;
  union { __hip_bfloat16 h[8]; uint4 u; } pk;
  if (g < 24) {
    int c0 = g * 8;
    const float* e = emb + xr[0] * 192 + c0;
#pragma unroll
    for (int j = 0; j < 8; ++j) pk.h[j] = __float2bfloat16(siluf(e[j]));
    *(uint4*)&cat[(size_t)t * 576 + c0] = pk.u;
  } else {
    int c0 = (g - 24) * 8;
#pragma unroll
    for (int j = 0; j < 8; ++j) {
      int c = c0 + j;
      float v = (c == 0) ? 1.f : ((c <= 160) ? (float)xr[c] : 0.f);
      pk.h[j] = __float2bfloat16(v);
    }
    *(uint4*)&Fb[(size_t)t * 192 + c0] = pk.u;
  }
}

// ---------------------------------------------------------------- MFMA GEMM
// m97 structure + T1 XCD swizzle (col-tile fastest). bf16 output only.
// Epilogue: C tile staged through LDS (2 x 64-row rounds, 136-elem pad) so
// stores are 8 coalesced dwordx4/thread instead of 64 scalar b16.
template <bool SILU = false>
__global__ __launch_bounds__(256) void gemm_mfma(
    const ushort* __restrict__ A, const ushort* __restrict__ W,
    const float* __restrict__ bias, __hip_bfloat16* __restrict__ C, int M,
    int N, int K, int ldc, int ntn) {
  __shared__ __align__(16) short SH[16384];  // As(8192) | Bs(8192); CS overlays
  short* Abuf = SH;
  short* Bbuf = SH + 8192;
  const int tid = threadIdx.x;
  const int lane = tid & 63;
  const int wid = tid >> 6;
  const int wr = wid >> 1, wc = wid & 1;
  const int nwg = gridDim.x;
  const int orig = blockIdx.x;
  const int qq = nwg >> 3, rr = nwg & 7;
  const int xcd = orig & 7;
  const int wgid = (xcd < rr ? xcd * (qq + 1) : rr * (qq + 1) + (xcd - rr) * qq)
                   + (orig >> 3);
  const int row0 = (wgid / ntn) * 128, col0 = (wgid % ntn) * 128;

  const int lrow = lane >> 2;       // 0..15
  const int lch = (lane & 3) * 8;
  const int frow = lane & 15;
  const int fk = (lane >> 4) * 8;

  const ushort* Abase = A + (size_t)(row0 + 32 * wid + lrow) * K + lch;
  const ushort* Wbase = W + (size_t)(col0 + 32 * wid + lrow) * K + lch;
  short* Al[2] = {Abuf + 32 * wid * 32, Abuf + 4096 + 32 * wid * 32};
  short* Bl[2] = {Bbuf + 32 * wid * 32, Bbuf + 4096 + 32 * wid * 32};

  f32x4 acc[4][4];
  const f32x4 z = {0.f, 0.f, 0.f, 0.f};
#pragma unroll
  for (int i = 0; i < 4; ++i)
#pragma unroll
    for (int j = 0; j < 4; ++j) acc[i][j] = z;

  const int T = K >> 5;
  gload16(Abase, Al[0]);
  gload16(Abase + (size_t)16 * K, Al[0] + 512);
  gload16(Wbase, Bl[0]);
  gload16(Wbase + (size_t)16 * K, Bl[0] + 512);

  for (int t = 0; t < T; ++t) {
    __syncthreads();
    if (t + 1 < T) {
      const ushort* An = Abase + (t + 1) * 32;
      const ushort* Wn = Wbase + (t + 1) * 32;
      short* Ad = Al[(t + 1) & 1];
      short* Bd = Bl[(t + 1) & 1];
      gload16(An, Ad);
      gload16(An + (size_t)16 * K, Ad + 512);
      gload16(Wn, Bd);
      gload16(Wn + (size_t)16 * K, Bd + 512);
    }
    const short* Ab = Abuf + (t & 1) * 4096;
    const short* Bb = Bbuf + (t & 1) * 4096;
    bf16x8 af[4], bfr[4];
#pragma unroll
    for (int i = 0; i < 4; ++i)
      af[i] = *(const bf16x8*)&Ab[(wr * 64 + i * 16 + frow) * 32 + fk];
#pragma unroll
    for (int j = 0; j < 4; ++j)
      bfr[j] = *(const bf16x8*)&Bb[(wc * 64 + j * 16 + frow) * 32 + fk];
#pragma unroll
    for (int i = 0; i < 4; ++i)
#pragma unroll
      for (int j = 0; j < 4; ++j)
        acc[i][j] = __builtin_amdgcn_mfma_f32_16x16x32_bf16(af[i], bfr[j],
                                                            acc[i][j], 0, 0, 0);
  }

  // ---- epilogue: 2 rounds of 64 rows staged via LDS, coalesced stores
  __hip_bfloat16* CSH = (__hip_bfloat16*)SH;  // [64][136] bf16
  const int orow = (lane >> 4) * 4;
  const int srow = tid >> 2;         // 0..63 (copy-out row)
  const int scb = (tid & 3) * 32;    // copy-out col base
#pragma unroll
  for (int p = 0; p < 2; ++p) {
    __syncthreads();  // K-loop reads / previous round copy-out complete
    if (wr == p) {
#pragma unroll
      for (int j = 0; j < 4; ++j) {
        const int col = wc * 64 + (lane & 15) + j * 16;
        const float bv = bias ? bias[col0 + col] : 0.f;
#pragma unroll
        for (int i = 0; i < 4; ++i)
#pragma unroll
          for (int r = 0; r < 4; ++r) {
            float v = acc[i][j][r] + bv;
            if constexpr (SILU) v = siluf(v);
            CSH[(i * 16 + orow + r) * 136 + col] = __float2bfloat16(v);
          }
      }
    }
    __syncthreads();
    const int grow = row0 + p * 64 + srow;
#pragma unroll
    for (int c = 0; c < 4; ++c) {
      bf16x8 v = *(const bf16x8*)&CSH[srow * 136 + scb + c * 8];
      *(bf16x8*)&C[(size_t)grow * ldc + col0 + scb + c * 8] = v;
    }
  }
}

// ---------------------------------------------------------------- fused GEMM
// BM=128 x full N=512 per block, 8 waves (512 thr) each 64x128 (acc 4x8).
// Epilogue: bias + LayerNorm(512) + silu from fp32 accs in-register.
// HEAD=false: write bf16 C. HEAD=true: + 9-dot head + activations -> out.
template <bool HEAD>
__global__ __launch_bounds__(512, 2) void gemm_ln_fused(
    const ushort* __restrict__ A, const ushort* __restrict__ W,
    const float* __restrict__ bias, const float* __restrict__ g,
    const float* __restrict__ b2, const float* __restrict__ hw,
    const float* __restrict__ hb, __hip_bfloat16* __restrict__ C,
    float* __restrict__ out, int K) {
  __shared__ __align__(16) short As[2][128 * 32];
  __shared__ __align__(16) short Bs[2][512 * 32];
  __shared__ float rs[4][128], rss[4][128];
  __shared__ float o9[4][128][9];
  const int tid = threadIdx.x;
  const int lane = tid & 63;
  const int wid = tid >> 6;            // 0..7
  const int wr = wid & 1, wc = wid >> 1;
  const int row0 = blockIdx.x * 128;
  const int frow = lane & 15;
  const int fk = (lane >> 4) * 8;

  const ushort* Abase =
      A + (size_t)(row0 + 16 * wid + (lane >> 2)) * K + (lane & 3) * 8;
  const ushort* Wbase = W + (size_t)(64 * wid + (lane >> 2)) * K + (lane & 3) * 8;
  short* Adst[2] = {&As[0][16 * wid * 32], &As[1][16 * wid * 32]};
  short* Bdst[2] = {&Bs[0][64 * wid * 32], &Bs[1][64 * wid * 32]};

  f32x4 acc[4][8];
  const f32x4 z = {0.f, 0.f, 0.f, 0.f};
#pragma unroll
  for (int i = 0; i < 4; ++i)
#pragma unroll
    for (int j = 0; j < 8; ++j) acc[i][j] = z;

  const int T = K >> 5;
  gload16(Abase, Adst[0]);
#pragma unroll
  for (int q = 0; q < 4; ++q)
    gload16(Wbase + (size_t)q * 16 * K, Bdst[0] + q * 16 * 32);

  for (int t = 0; t < T; ++t) {
    __syncthreads();
    if (t + 1 < T) {
      const ushort* An = Abase + (t + 1) * 32;
      const ushort* Wn = Wbase + (t + 1) * 32;
      short* Ad = Adst[(t + 1) & 1];
      short* Bd = Bdst[(t + 1) & 1];
      gload16(An, Ad);
#pragma unroll
      for (int q = 0; q < 4; ++q)
        gload16(Wn + (size_t)q * 16 * K, Bd + q * 16 * 32);
    }
    const short* Ab = As[t & 1];
    const short* Bb = Bs[t & 1];
    bf16x8 af[4], bfr[8];
#pragma unroll
    for (int i = 0; i < 4; ++i)
      af[i] = *(const bf16x8*)&Ab[(wr * 64 + i * 16 + frow) * 32 + fk];
#pragma unroll
    for (int j = 0; j < 8; ++j)
      bfr[j] = *(const bf16x8*)&Bb[(wc * 128 + j * 16 + frow) * 32 + fk];
#pragma unroll
    for (int i = 0; i < 4; ++i)
#pragma unroll
      for (int j = 0; j < 8; ++j)
        acc[i][j] = __builtin_amdgcn_mfma_f32_16x16x32_bf16(af[i], bfr[j],
                                                            acc[i][j], 0, 0, 0);
  }

  // ---- epilogue: bias + LN stats
  float bv[8], gv[8], b2v[8];
#pragma unroll
  for (int j = 0; j < 8; ++j) {
    int col = wc * 128 + (lane & 15) + j * 16;
    bv[j] = bias[col];
    gv[j] = g[col];
    b2v[j] = b2[col];
  }
  float sum_[4][4], sq_[4][4];
#pragma unroll
  for (int i = 0; i < 4; ++i)
#pragma unroll
    for (int r = 0; r < 4; ++r) { sum_[i][r] = 0.f; sq_[i][r] = 0.f; }
#pragma unroll
  for (int i = 0; i < 4; ++i)
#pragma unroll
    for (int j = 0; j < 8; ++j)
#pragma unroll
      for (int r = 0; r < 4; ++r) {
        float v = acc[i][j][r] + bv[j];
        acc[i][j][r] = v;
        sum_[i][r] += v;
        sq_[i][r] += v * v;
      }
#pragma unroll
  for (int i = 0; i < 4; ++i)
#pragma unroll
    for (int r = 0; r < 4; ++r)
#pragma unroll
      for (int off = 1; off < 16; off <<= 1) {
        sum_[i][r] += __shfl_xor(sum_[i][r], off, 64);
        sq_[i][r] += __shfl_xor(sq_[i][r], off, 64);
      }
  if ((lane & 15) == 0) {
#pragma unroll
    for (int i = 0; i < 4; ++i)
#pragma unroll
      for (int r = 0; r < 4; ++r) {
        int lr = wr * 64 + (lane >> 4) * 4 + i * 16 + r;
        rs[wc][lr] = sum_[i][r];
        rss[wc][lr] = sq_[i][r];
      }
  }
  __syncthreads();
#pragma unroll
  for (int i = 0; i < 4; ++i)
#pragma unroll
    for (int r = 0; r < 4; ++r) {
      int lr = wr * 64 + (lane >> 4) * 4 + i * 16 + r;
      float S = rs[0][lr] + rs[1][lr] + rs[2][lr] + rs[3][lr];
      float SS = rss[0][lr] + rss[1][lr] + rss[2][lr] + rss[3][lr];
      float mean = S * (1.f / 512.f);
      float var = SS * (1.f / 512.f) - mean * mean;
      float rstd = rsqrtf(var + 1e-5f);
#pragma unroll
      for (int j = 0; j < 8; ++j) {
        float y = (acc[i][j][r] - mean) * rstd * gv[j] + b2v[j];
        acc[i][j][r] = siluf(y);
      }
    }

  if constexpr (!HEAD) {
#pragma unroll
    for (int i = 0; i < 4; ++i)
#pragma unroll
      for (int r = 0; r < 4; ++r) {
        int grow = row0 + wr * 64 + (lane >> 4) * 4 + i * 16 + r;
#pragma unroll
        for (int j = 0; j < 8; ++j)
          C[(size_t)grow * 512 + wc * 128 + (lane & 15) + j * 16] =
              __float2bfloat16(acc[i][j][r]);
      }
  } else {
#pragma unroll
    for (int r9 = 0; r9 < 9; ++r9) {
      float hw8[8];
#pragma unroll
      for (int j = 0; j < 8; ++j)
        hw8[j] = hw[r9 * 512 + wc * 128 + (lane & 15) + j * 16];
      float pacc[4][4];
#pragma unroll
      for (int i = 0; i < 4; ++i)
#pragma unroll
        for (int r = 0; r < 4; ++r) {
          float p = 0.f;
#pragma unroll
          for (int j = 0; j < 8; ++j) p = fmaf(acc[i][j][r], hw8[j], p);
#pragma unroll
          for (int off = 1; off < 16; off <<= 1) p += __shfl_xor(p, off, 64);
          pacc[i][r] = p;
        }
      if ((lane & 15) == 0) {
#pragma unroll
        for (int i = 0; i < 4; ++i)
#pragma unroll
          for (int r = 0; r < 4; ++r) {
            int lr = wr * 64 + (lane >> 4) * 4 + i * 16 + r;
            o9[wc][lr][r9] = pacc[i][r];
          }
      }
    }
    __syncthreads();
    if (tid < 128) {
      float raw[9];
#pragma unroll
      for (int r9 = 0; r9 < 9; ++r9)
        raw[r9] = o9[0][tid][r9] + o9[1][tid][r9] + o9[2][tid][r9] +
                  o9[3][tid][r9] + hb[r9];
      float* op = out + (size_t)(row0 + tid) * 9;
      op[0] = fmaxf(raw[0], 0.f) + log1pf(expf(-fabsf(raw[0])));
      op[1] = fmaxf(raw[1], 0.f) + log1pf(expf(-fabsf(raw[1])));
      op[2] = 1.f / (1.f + expf(-raw[2]));
      op[3] = 1.f / (1.f + expf(-raw[3]));
      op[4] = 1.f / (1.f + expf(-raw[4]));
      float mx = fmaxf(fmaxf(raw[5], raw[6]), fmaxf(raw[7], raw[8]));
      float e0 = expf(raw[5] - mx), e1 = expf(raw[6] - mx);
      float e2 = expf(raw[7] - mx), e3 = expf(raw[8] - mx);
      float inv = 1.f / (e0 + e1 + e2 + e3);
      op[5] = e0 * inv; op[6] = e1 * inv; op[7] = e2 * inv; op[8] = e3 * inv;
    }
  }
}

// ---------------------------------------------------------------- attn (MFMA)
// One block per (b,h,window-block): 4 waves x 32 queries. KV chunks of 64 keys,
// double-buffered with async-split staging; one barrier per chunk.
// Wave-uniform subtile skip: fully masked 32-key subtiles (exact zeros)
// contribute nothing and are skipped.
__global__ __launch_bounds__(256) void attn_kernel(
    const __hip_bfloat16* __restrict__ qkv, const float2* __restrict__ tab,
    __hip_bfloat16* __restrict__ o_out) {
  __shared__ __align__(16) short Kc[2][64 * 72];   // [key 64][dim 64 pad 72]
  __shared__ __align__(16) short Vt[2][64 * 72];   // [dim 64][key 64 pad 72]
  __shared__ __align__(16) float rbuf[4][32];
  const int blk = blockIdx.x;
  const int nbIdx = blk & 63;
  const int h = (blk >> 6) & 7;
  const int b = blk >> 9;
  const int tid = threadIdx.x;
  const int w = tid >> 6;
  const int lane = tid & 63;
  const int lq = lane & 31;
  const int hi = lane >> 5;
  const size_t seqBase = (size_t)b * LSEQ;
  const int qi = w * 32 + lq;
  const int qtok = nbIdx * 128 + qi;
  const int qmin = w * 32;

  const ushort* qkvu = (const ushort*)qkv;

  bf16x8 qf[4];
  {
    const ushort* Qrow = qkvu + (seqBase + qtok) * 1536 + h * 64;
#pragma unroll
    for (int s = 0; s < 4; ++s) {
      int dim0 = 16 * s + 8 * hi;
      bf16x8 qv = *(const bf16x8*)(Qrow + dim0);
      const float4* tp = (const float4*)(tab + qtok * 32 + dim0 / 2);
      float4 t01 = tp[0], t23 = tp[1];
      float cs[4] = {t01.x, t01.z, t23.x, t23.z};
      float sn[4] = {t01.y, t01.w, t23.y, t23.w};
      union { uint u[4]; bf16x8 v; } pk;
#pragma unroll
      for (int j = 0; j < 4; ++j) {
        float x1 = bf2f((ushort)qv[2 * j]);
        float x2 = bf2f((ushort)qv[2 * j + 1]);
        float r0 = (x1 * cs[j] - x2 * sn[j]) * 0.125f;
        float r1 = (x1 * sn[j] + x2 * cs[j]) * 0.125f;
        pk.u[j] = cvtpk_bf16(r0, r1);
      }
      qf[s] = pk.v;
    }
  }

  const f32x16 Z16 = {0.f};
  f32x16 oa0 = Z16, oa1 = Z16;
  float m0 = -3.0e38f, l = 0.f;

  const int cstart = (nbIdx == 0) ? 2 : 0;
  const int cw0 = (w >= 2) ? 1 : 0;
  const int cw1 = (w >= 2) ? 3 : 2;

  const int skk = tid >> 2;
  const int sd0 = (tid & 3) * 16;

  bf16x8 kreg0, kreg1, vreg0, vreg1;

  auto issue = [&](int c) {
    int ktok = (nbIdx - 1) * 128 + c * 64 + skk;
    const ushort* base = qkvu + (seqBase + ktok) * 1536 + h * 64 + sd0;
    kreg0 = *(const bf16x8*)(base + 512);
    kreg1 = *(const bf16x8*)(base + 512 + 8);
    vreg0 = *(const bf16x8*)(base + 1024);
    vreg1 = *(const bf16x8*)(base + 1024 + 8);
  };

  auto write_chunk = [&](int c) {
    short* Kb = Kc[c & 1];
    short* Vb = Vt[c & 1];
    int ktok = (nbIdx - 1) * 128 + c * 64 + skk;
    const float4* tp = (const float4*)(tab + ktok * 32 + (sd0 >> 1));
    float4 t0 = tp[0], t1 = tp[1], t2 = tp[2], t3 = tp[3];
    const int swk = ((skk >> 3) & 3) << 5;
    {
      float cs[4] = {t0.x, t0.z, t1.x, t1.z};
      float sn[4] = {t0.y, t0.w, t1.y, t1.w};
      union { uint u[4]; bf16x8 v; } pk;
#pragma unroll
      for (int j = 0; j < 4; ++j) {
        float x1 = bf2f((ushort)kreg0[2 * j]);
        float x2 = bf2f((ushort)kreg0[2 * j + 1]);
        pk.u[j] = cvtpk_bf16(x1 * cs[j] - x2 * sn[j], x1 * sn[j] + x2 * cs[j]);
      }
      *(bf16x8*)((char*)Kb + skk * 144 + ((sd0 * 2) ^ swk)) = pk.v;
    }
    {
      float cs[4] = {t2.x, t2.z, t3.x, t3.z};
      float sn[4] = {t2.y, t2.w, t3.y, t3.w};
      union { uint u[4]; bf16x8 v; } pk;
#pragma unroll
      for (int j = 0; j < 4; ++j) {
        float x1 = bf2f((ushort)kreg1[2 * j]);
        float x2 = bf2f((ushort)kreg1[2 * j + 1]);
        pk.u[j] = cvtpk_bf16(x1 * cs[j] - x2 * sn[j], x1 * sn[j] + x2 * cs[j]);
      }
      *(bf16x8*)((char*)Kb + skk * 144 + (((sd0 + 8) * 2) ^ swk)) = pk.v;
    }
#pragma unroll
    for (int j = 0; j < 8; ++j) {
      int d0 = sd0 + j;
      *(short*)((char*)Vb + d0 * 144 +
                ((skk * 2) ^ (((d0 >> 4) & 3) << 5))) = vreg0[j];
      int d1 = sd0 + 8 + j;
      *(short*)((char*)Vb + d1 * 144 +
                ((skk * 2) ^ (((d1 >> 4) & 3) << 5))) = vreg1[j];
    }
  };

  issue(cstart);
  write_chunk(cstart);

  for (int c = cstart; c < 4; ++c) {
    if (c < 3) issue(c + 1);
    __syncthreads();
    if (c >= cw0 && c <= cw1) {
      const char* Kb = (const char*)Kc[c & 1];
      const char* Vb = (const char*)Vt[c & 1];

      // wave-uniform subtile validity: keys [ks, ks+31] vs [qmin, qmin+159]
      bool val[2];
#pragma unroll
      for (int t2 = 0; t2 < 2; ++t2) {
        int ks = c * 64 + 32 * t2;
        val[t2] = (ks + 31 >= qmin) && (ks <= qmin + 159);
      }

      float p2[2][16];
      float pmax = -3.0e38f;
#pragma unroll
      for (int t2 = 0; t2 < 2; ++t2) {
        if (!val[t2]) continue;
        bf16x8 ka[4];
#pragma unroll
        for (int s = 0; s < 4; ++s) {
          int kk = 32 * t2 + lq;
          int byteoff =
              kk * 144 + ((32 * s + 16 * hi) ^ (((kk >> 3) & 3) << 5));
          ka[s] = *(const bf16x8*)(Kb + byteoff);
        }
        f32x16 st = Z16;
#pragma unroll
        for (int s = 0; s < 4; ++s)
          st = __builtin_amdgcn_mfma_f32_32x32x16_bf16(ka[s], qf[s], st, 0, 0, 0);
#pragma unroll
        for (int r = 0; r < 16; ++r) {
          int key = c * 64 + 32 * t2 + (r & 3) + 8 * (r >> 2) + 4 * hi;
          float sv = st[r];
          bool act = (key >= qi) && (key <= qi + 128);
          sv = act ? sv : -1.0e30f;
          p2[t2][r] = sv;
          pmax = fmaxf(pmax, sv);
        }
      }
      pmax = fmaxf(pmax, __shfl_xor(pmax, 32));
      if (__any(pmax > m0 + 8.f)) {
        float nm = fmaxf(m0, pmax);
        float rr2 = __expf(m0 - nm);
        l *= rr2;
        m0 = nm;
        rbuf[w][lq] = rr2;
        asm volatile("s_waitcnt lgkmcnt(0)" ::: "memory");
#pragma unroll
        for (int a = 0; a < 4; ++a) {
          f32x4 r4 = *(const f32x4*)&rbuf[w][8 * a + 4 * hi];
#pragma unroll
          for (int j = 0; j < 4; ++j) {
            oa0[4 * a + j] *= r4[j];
            oa1[4 * a + j] *= r4[j];
          }
        }
      }
      float lsum = 0.f;
#pragma unroll
      for (int t2 = 0; t2 < 2; ++t2) {
        if (!val[t2]) continue;
#pragma unroll
        for (int r = 0; r < 16; ++r) {
          float p = __expf(p2[t2][r] - m0);
          p2[t2][r] = p;
          lsum += p;
        }
      }
      l += lsum + __shfl_xor(lsum, 32);

#pragma unroll
      for (int t2 = 0; t2 < 2; ++t2) {
        if (!val[t2]) continue;
        union { uint u[4]; bf16x8 v; } pa[2];
#pragma unroll
        for (int sl = 0; sl < 2; ++sl) {
          const float* pp = &p2[t2][8 * sl];
          uint a0 = cvtpk_bf16(pp[0], pp[1]);
          uint a1 = cvtpk_bf16(pp[2], pp[3]);
          uint b0 = cvtpk_bf16(pp[4], pp[5]);
          uint b1 = cvtpk_bf16(pp[6], pp[7]);
          perm32swap(a0, b0);
          perm32swap(a1, b1);
          pa[sl].u[0] = a0; pa[sl].u[1] = a1;
          pa[sl].u[2] = b0; pa[sl].u[3] = b1;
        }
#pragma unroll
        for (int sl = 0; sl < 2; ++sl) {
          int slot = 2 * t2 + sl;
          {
            int d = lq;
            int byteoff =
                d * 144 + ((32 * slot + 16 * hi) ^ (((d >> 4) & 3) << 5));
            bf16x8 vb = *(const bf16x8*)(Vb + byteoff);
            oa0 = __builtin_amdgcn_mfma_f32_32x32x16_bf16(pa[sl].v, vb, oa0, 0, 0, 0);
          }
          {
            int d = 32 + lq;
            int byteoff =
                d * 144 + ((32 * slot + 16 * hi) ^ (((d >> 4) & 3) << 5));
            bf16x8 vb = *(const bf16x8*)(Vb + byteoff);
            oa1 = __builtin_amdgcn_mfma_f32_32x32x16_bf16(pa[sl].v, vb, oa1, 0, 0, 0);
          }
        }
      }
    }
    if (c < 3) write_chunk(c + 1);
  }

  rbuf[w][lq] = 1.f / l;
  asm volatile("s_waitcnt lgkmcnt(0)" ::: "memory");
  const int q0 = nbIdx * 128 + 32 * w;
#pragma unroll
  for (int a = 0; a < 4; ++a) {
    f32x4 r4 = *(const f32x4*)&rbuf[w][8 * a + 4 * hi];
#pragma unroll
    for (int j = 0; j < 4; ++j) {
      int tok = q0 + 8 * a + 4 * hi + j;
      __hip_bfloat16* orow = o_out + (seqBase + tok) * 512 + h * 64;
      orow[lq] = __float2bfloat16(oa0[4 * a + j] * r4[j]);
      orow[32 + lq] = __float2bfloat16(oa1[4 * a + j] * r4[j]);
    }
  }
}

// ---------------------------------------------------------------- launch
// Workspace layout (~133 MB peak):
//   w16: bf16 [inst | outp | qkv(permuted) | wcat] ; rope table (2MB)
//   R1 (96MB): {cat M*576 | Fb M*192} -> qkvb M*1536
//   R2 (32MB): hb bf16 -> att bf16
extern "C" void kernel_launch(void* const* d_in, const int* in_sizes, int n_in,
                              void* d_out, int out_size, void* d_ws,
                              size_t ws_size, hipStream_t stream) {
  const float* emb = (const float*)d_in[0];
  const float* reg_w = (const float*)d_in[1];
  const float* reg_b = (const float*)d_in[2];
  const float* br_w = (const float*)d_in[3];
  const float* br_b = (const float*)d_in[4];
  const float* mem_w = (const float*)d_in[5];
  const float* mem_b = (const float*)d_in[6];
  const float* inst_w = (const float*)d_in[7];
  const float* inst_b = (const float*)d_in[8];
  const float* ln1_g = (const float*)d_in[9];
  const float* ln1_b = (const float*)d_in[10];
  const float* qkv_w = (const float*)d_in[11];
  const float* outp_w = (const float*)d_in[12];
  const float* outp_b = (const float*)d_in[13];
  const float* ln2_g = (const float*)d_in[14];
  const float* ln2_b = (const float*)d_in[15];
  const float* head_w = (const float*)d_in[16];
  const float* head_b = (const float*)d_in[17];
  const int* x = (const int*)d_in[18];
  float* out = (float*)d_out;

  const int M = M_TOK;
  char* wsb = (char*)d_ws;
  __hip_bfloat16* w16 = (__hip_bfloat16*)wsb;
  __hip_bfloat16* w1 = w16;                        // inst
  __hip_bfloat16* w3 = w16 + NW1;                  // outp
  __hip_bfloat16* w2 = w16 + NW1 + NW3;            // qkv (permuted)
  __hip_bfloat16* wcat = w16 + NW1 + NW3 + NW2;    // feature proj
  size_t woff = ((size_t)(NW1 + NW2 + NW3 + NW4) * 2 + 255) & ~(size_t)255;
  float2* tab = (float2*)(wsb + woff);             // 2MB
  size_t toff = woff + (size_t)NTAB * 8;
  char* r1 = wsb + toff;                           // 96 MB region
  char* r2 = r1 + (size_t)M * 1536 * 2;            // 32 MB region
  __hip_bfloat16* cat = (__hip_bfloat16*)r1;       // M*576
  __hip_bfloat16* Fb = (__hip_bfloat16*)(r1 + (size_t)M * 576 * 2);  // M*192
  __hip_bfloat16* qkvb = (__hip_bfloat16*)r1;      // M*1536
  __hip_bfloat16* hb = (__hip_bfloat16*)r2;        // M*512
  __hip_bfloat16* att = (__hip_bfloat16*)r2;       // M*512

  // 0. all weight conversion + rope table (one kernel)
  const int setup_tot = NW1 + NW3 + NW2 + NW4 + NTAB;
  setup_kernel<<<(setup_tot + 255) / 256, 256, 0, stream>>>(
      inst_w, outp_w, qkv_w, reg_w, reg_b, br_w, br_b, mem_w, mem_b, w16, tab);
  // 1. prep: cat[:,0:192] = silu(emb[tid]) ; Fb = [1, feats, 0]
  prep_kernel<<<(M * 48) / 256, 256, 0, stream>>>(x, emb, cat, Fb);
  // 1b. feature proj: cat[:,192:576] = silu(Fb @ wcat^T)
  gemm_mfma<true><<<(M / 128) * 3, 256, 0, stream>>>(
      (const ushort*)Fb, (const ushort*)wcat, nullptr, cat + 192, M, 384, 192,
      576, 3);
  // 2. inst proj + LN1 + silu fused: hb = silu(LN(cat @ w1^T + b))
  gemm_ln_fused<false><<<M / 128, 512, 0, stream>>>(
      (const ushort*)cat, (const ushort*)w1, inst_b, ln1_g, ln1_b, nullptr,
      nullptr, hb, nullptr, 576);
  // 3. qkv proj (permuted cols): hb @ w2^T -> qkvb planes [Q|K|V]
  gemm_mfma<false><<<(M / 128) * 12, 256, 0, stream>>>(
      (const ushort*)hb, (const ushort*)w2, nullptr, qkvb, M, 1536, 512, 1536,
      12);
  // 4. attention (MFMA) -> att (bf16, [M][512] heads concatenated)
  attn_kernel<<<BATCH * 8 * 64, 256, 0, stream>>>(qkvb, tab, att);
  // 5. outp proj + LN2 + silu + head + activations fused -> out
  gemm_ln_fused<true><<<M / 128, 512, 0, stream>>>(
      (const ushort*)att, (const ushort*)w3, outp_b, ln2_g, ln2_b, head_w,
      head_b, nullptr, out, 512);
}

// Round 16
// 252.905 us; speedup vs baseline: 1.0875x; 1.0875x over previous
//
#include <hip/hip_runtime.h>
#include <hip/hip_bf16.h>
#include <math.h>
#include <type_traits>

#define LSEQ 8192
#define BATCH 4
#define M_TOK (BATCH * LSEQ)

typedef __attribute__((ext_vector_type(8))) short bf16x8;   // 8 bf16 = 4 VGPR
typedef __attribute__((ext_vector_type(4))) float f32x4;
typedef __attribute__((ext_vector_type(16))) float f32x16;

// ---------------------------------------------------------------- helpers
__device__ __forceinline__ float siluf(float x) {
  return x / (1.f + __expf(-x));
}

__device__ __forceinline__ float bf2f(uint u16) {
  union { float f; uint u; } c;
  c.u = u16 << 16;
  return c.f;
}

__device__ __forceinline__ uint cvtpk_bf16(float lo, float hi) {
  uint r;
  asm volatile("v_cvt_pk_bf16_f32 %0, %1, %2" : "=v"(r) : "v"(lo), "v"(hi));
  return r;
}

// swaps hi 32 lanes of a with lo 32 lanes of b
__device__ __forceinline__ void perm32swap(uint& a, uint& b) {
  asm volatile("v_permlane32_swap_b32 %0, %1" : "+v"(a), "+v"(b));
}

// async global->LDS, 16B per lane; LDS dest = wave-uniform base + lane*16
__device__ __forceinline__ void gload16(const ushort* g, short* l) {
  __builtin_amdgcn_global_load_lds(
      (const __attribute__((address_space(1))) void*)g,
      (__attribute__((address_space(3))) void*)l, 16, 0, 0);
}

// ---------------------------------------------------------------- setup
#define NW1 (512 * 576)
#define NW3 (512 * 512)
#define NW2 (1536 * 512)
#define NW4 (384 * 192)
#define NTAB (8192 * 32)

__global__ __launch_bounds__(256) void setup_kernel(
    const float* __restrict__ inst_w, const float* __restrict__ outp_w,
    const float* __restrict__ qkv_w, const float* __restrict__ reg_w,
    const float* __restrict__ reg_b, const float* __restrict__ br_w,
    const float* __restrict__ br_b, const float* __restrict__ mem_w,
    const float* __restrict__ mem_b, __hip_bfloat16* __restrict__ w16,
    float2* __restrict__ tab) {
  int i = blockIdx.x * 256 + threadIdx.x;
  if (i < NW1) {
    w16[i] = __float2bfloat16(inst_w[i]);
    return;
  }
  i -= NW1;
  if (i < NW3) {
    w16[NW1 + i] = __float2bfloat16(outp_w[i]);
    return;
  }
  i -= NW3;
  if (i < NW2) {
    // qkv row permutation: out row n' = which*512 + h*64 + d
    // from src row n = h*192 + d*3 + which -> qkvb planes [Q|K|V]
    int np = i / 512, k = i % 512;
    int which = np >> 9, rem = np & 511;
    int h = rem >> 6, d = rem & 63;
    int n = h * 192 + d * 3 + which;
    w16[NW1 + NW3 + i] = __float2bfloat16(qkv_w[n * 512 + k]);
    return;
  }
  i -= NW2;
  if (i < NW4) {
    // Wcat[384][192]: F cols [0]=1(bias),[1..64]=reg,[65..128]=mem,[129..160]=br
    int o = i / 192, c = i % 192;
    float v = 0.f;
    if (o < 128) {
      if (c == 0) v = reg_b[o];
      else if (c <= 64) v = reg_w[o * 64 + (c - 1)];
    } else if (o < 256) {
      int oo = o - 128;
      if (c == 0) v = br_b[oo];
      else if (c >= 129 && c <= 160) v = br_w[oo * 32 + (c - 129)];
    } else {
      int oo = o - 256;
      if (c == 0) v = mem_b[oo];
      else if (c >= 65 && c <= 128) v = mem_w[oo * 64 + (c - 65)];
    }
    w16[NW1 + NW3 + NW2 + i] = __float2bfloat16(v);
    return;
  }
  i -= NW4;
  if (i < NTAB) {
    int pos = i >> 5, p = i & 31;
    float inv = expf(-(float)p * 0.28782313662f);  // ln(10000)/32
    float sn, cs;
    sincosf((float)pos * inv, &sn, &cs);
    tab[i] = make_float2(cs, sn);
  }
}

// ---------------------------------------------------------------- prep
__global__ __launch_bounds__(256) void prep_kernel(
    const int* __restrict__ x, const float* __restrict__ emb,
    __hip_bfloat16* __restrict__ cat, __hip_bfloat16* __restrict__ Fb) {
  int gid = blockIdx.x * 256 + threadIdx.x;
  int t = gid / 48;
  int g = gid % 48;
  if (t >= M_TOK) return;
  const int* xr = x + (size_t)t * 161;
  union { __hip_bfloat16 h[8]; uint4 u; } pk;
  if (g < 24) {
    int c0 = g * 8;
    const float* e = emb + xr[0] * 192 + c0;
#pragma unroll
    for (int j = 0; j < 8; ++j) pk.h[j] = __float2bfloat16(siluf(e[j]));
    *(uint4*)&cat[(size_t)t * 576 + c0] = pk.u;
  } else {
    int c0 = (g - 24) * 8;
#pragma unroll
    for (int j = 0; j < 8; ++j) {
      int c = c0 + j;
      float v = (c == 0) ? 1.f : ((c <= 160) ? (float)xr[c] : 0.f);
      pk.h[j] = __float2bfloat16(v);
    }
    *(uint4*)&Fb[(size_t)t * 192 + c0] = pk.u;
  }
}

// ---------------------------------------------------------------- MFMA GEMM
// m97 structure + T1 XCD swizzle (col-tile fastest). Used for feat + qkv.
template <typename OT, bool SILU = false>
__global__ __launch_bounds__(256) void gemm_mfma(
    const ushort* __restrict__ A, const ushort* __restrict__ W,
    const float* __restrict__ bias, OT* __restrict__ C, int M, int N, int K,
    int ldc, int ntn) {
  __shared__ __align__(16) short As[2][128 * 32];
  __shared__ __align__(16) short Bs[2][128 * 32];
  const int tid = threadIdx.x;
  const int lane = tid & 63;
  const int wid = tid >> 6;
  const int wr = wid >> 1, wc = wid & 1;
  const int nwg = gridDim.x;
  const int orig = blockIdx.x;
  const int qq = nwg >> 3, rr = nwg & 7;
  const int xcd = orig & 7;
  const int wgid = (xcd < rr ? xcd * (qq + 1) : rr * (qq + 1) + (xcd - rr) * qq)
                   + (orig >> 3);
  const int row0 = (wgid / ntn) * 128, col0 = (wgid % ntn) * 128;

  const int lrow = lane >> 2;       // 0..15
  const int lch = (lane & 3) * 8;
  const int frow = lane & 15;
  const int fk = (lane >> 4) * 8;

  const ushort* Abase = A + (size_t)(row0 + 32 * wid + lrow) * K + lch;
  const ushort* Wbase = W + (size_t)(col0 + 32 * wid + lrow) * K + lch;
  short* Al[2] = {&As[0][32 * wid * 32], &As[1][32 * wid * 32]};
  short* Bl[2] = {&Bs[0][32 * wid * 32], &Bs[1][32 * wid * 32]};

  f32x4 acc[4][4];
  const f32x4 z = {0.f, 0.f, 0.f, 0.f};
#pragma unroll
  for (int i = 0; i < 4; ++i)
#pragma unroll
    for (int j = 0; j < 4; ++j) acc[i][j] = z;

  const int T = K >> 5;
  gload16(Abase, Al[0]);
  gload16(Abase + (size_t)16 * K, Al[0] + 512);
  gload16(Wbase, Bl[0]);
  gload16(Wbase + (size_t)16 * K, Bl[0] + 512);

  for (int t = 0; t < T; ++t) {
    __syncthreads();
    if (t + 1 < T) {
      const ushort* An = Abase + (t + 1) * 32;
      const ushort* Wn = Wbase + (t + 1) * 32;
      short* Ad = Al[(t + 1) & 1];
      short* Bd = Bl[(t + 1) & 1];
      gload16(An, Ad);
      gload16(An + (size_t)16 * K, Ad + 512);
      gload16(Wn, Bd);
      gload16(Wn + (size_t)16 * K, Bd + 512);
    }
    const short* Ab = As[t & 1];
    const short* Bb = Bs[t & 1];
    bf16x8 af[4], bfr[4];
#pragma unroll
    for (int i = 0; i < 4; ++i)
      af[i] = *(const bf16x8*)&Ab[(wr * 64 + i * 16 + frow) * 32 + fk];
#pragma unroll
    for (int j = 0; j < 4; ++j)
      bfr[j] = *(const bf16x8*)&Bb[(wc * 64 + j * 16 + frow) * 32 + fk];
#pragma unroll
    for (int i = 0; i < 4; ++i)
#pragma unroll
      for (int j = 0; j < 4; ++j)
        acc[i][j] = __builtin_amdgcn_mfma_f32_16x16x32_bf16(af[i], bfr[j],
                                                            acc[i][j], 0, 0, 0);
  }

  const int crow0 = row0 + wr * 64 + (lane >> 4) * 4;
  const int ccol0 = col0 + wc * 64 + (lane & 15);
#pragma unroll
  for (int j = 0; j < 4; ++j) {
    const int col = ccol0 + j * 16;
    const float bv = bias ? bias[col] : 0.f;
#pragma unroll
    for (int i = 0; i < 4; ++i) {
#pragma unroll
      for (int r = 0; r < 4; ++r) {
        float v = acc[i][j][r] + bv;
        if constexpr (SILU) v = siluf(v);
        size_t off = (size_t)(crow0 + i * 16 + r) * ldc + col;
        if constexpr (std::is_same<OT, float>::value) {
          C[off] = v;
        } else {
          C[off] = __float2bfloat16(v);
        }
      }
    }
  }
}

// ---------------------------------------------------------------- fused GEMM
// BM=128 x full N=512 per block, 8 waves (512 thr) each 64x128 (acc 4x8).
// Epilogue: bias + LayerNorm(512) + silu from fp32 accs in-register.
// HEAD=false: write bf16 C. HEAD=true: + 9-dot head + activations -> out.
template <bool HEAD>
__global__ __launch_bounds__(512, 2) void gemm_ln_fused(
    const ushort* __restrict__ A, const ushort* __restrict__ W,
    const float* __restrict__ bias, const float* __restrict__ g,
    const float* __restrict__ b2, const float* __restrict__ hw,
    const float* __restrict__ hb, __hip_bfloat16* __restrict__ C,
    float* __restrict__ out, int K) {
  __shared__ __align__(16) short As[2][128 * 32];
  __shared__ __align__(16) short Bs[2][512 * 32];
  __shared__ float rs[4][128], rss[4][128];
  __shared__ float o9[4][128][9];
  const int tid = threadIdx.x;
  const int lane = tid & 63;
  const int wid = tid >> 6;            // 0..7
  const int wr = wid & 1, wc = wid >> 1;
  const int row0 = blockIdx.x * 128;
  const int frow = lane & 15;
  const int fk = (lane >> 4) * 8;

  const ushort* Abase =
      A + (size_t)(row0 + 16 * wid + (lane >> 2)) * K + (lane & 3) * 8;
  const ushort* Wbase = W + (size_t)(64 * wid + (lane >> 2)) * K + (lane & 3) * 8;
  short* Adst[2] = {&As[0][16 * wid * 32], &As[1][16 * wid * 32]};
  short* Bdst[2] = {&Bs[0][64 * wid * 32], &Bs[1][64 * wid * 32]};

  f32x4 acc[4][8];
  const f32x4 z = {0.f, 0.f, 0.f, 0.f};
#pragma unroll
  for (int i = 0; i < 4; ++i)
#pragma unroll
    for (int j = 0; j < 8; ++j) acc[i][j] = z;

  const int T = K >> 5;
  gload16(Abase, Adst[0]);
#pragma unroll
  for (int q = 0; q < 4; ++q)
    gload16(Wbase + (size_t)q * 16 * K, Bdst[0] + q * 16 * 32);

  for (int t = 0; t < T; ++t) {
    __syncthreads();
    if (t + 1 < T) {
      const ushort* An = Abase + (t + 1) * 32;
      const ushort* Wn = Wbase + (t + 1) * 32;
      short* Ad = Adst[(t + 1) & 1];
      short* Bd = Bdst[(t + 1) & 1];
      gload16(An, Ad);
#pragma unroll
      for (int q = 0; q < 4; ++q)
        gload16(Wn + (size_t)q * 16 * K, Bd + q * 16 * 32);
    }
    const short* Ab = As[t & 1];
    const short* Bb = Bs[t & 1];
    bf16x8 af[4], bfr[8];
#pragma unroll
    for (int i = 0; i < 4; ++i)
      af[i] = *(const bf16x8*)&Ab[(wr * 64 + i * 16 + frow) * 32 + fk];
#pragma unroll
    for (int j = 0; j < 8; ++j)
      bfr[j] = *(const bf16x8*)&Bb[(wc * 128 + j * 16 + frow) * 32 + fk];
#pragma unroll
    for (int i = 0; i < 4; ++i)
#pragma unroll
      for (int j = 0; j < 8; ++j)
        acc[i][j] = __builtin_amdgcn_mfma_f32_16x16x32_bf16(af[i], bfr[j],
                                                            acc[i][j], 0, 0, 0);
  }

  // ---- epilogue: bias + LN stats
  float bv[8], gv[8], b2v[8];
#pragma unroll
  for (int j = 0; j < 8; ++j) {
    int col = wc * 128 + (lane & 15) + j * 16;
    bv[j] = bias[col];
    gv[j] = g[col];
    b2v[j] = b2[col];
  }
  float sum_[4][4], sq_[4][4];
#pragma unroll
  for (int i = 0; i < 4; ++i)
#pragma unroll
    for (int r = 0; r < 4; ++r) { sum_[i][r] = 0.f; sq_[i][r] = 0.f; }
#pragma unroll
  for (int i = 0; i < 4; ++i)
#pragma unroll
    for (int j = 0; j < 8; ++j)
#pragma unroll
      for (int r = 0; r < 4; ++r) {
        float v = acc[i][j][r] + bv[j];
        acc[i][j][r] = v;
        sum_[i][r] += v;
        sq_[i][r] += v * v;
      }
#pragma unroll
  for (int i = 0; i < 4; ++i)
#pragma unroll
    for (int r = 0; r < 4; ++r)
#pragma unroll
      for (int off = 1; off < 16; off <<= 1) {
        sum_[i][r] += __shfl_xor(sum_[i][r], off, 64);
        sq_[i][r] += __shfl_xor(sq_[i][r], off, 64);
      }
  if ((lane & 15) == 0) {
#pragma unroll
    for (int i = 0; i < 4; ++i)
#pragma unroll
      for (int r = 0; r < 4; ++r) {
        int lr = wr * 64 + (lane >> 4) * 4 + i * 16 + r;
        rs[wc][lr] = sum_[i][r];
        rss[wc][lr] = sq_[i][r];
      }
  }
  __syncthreads();
#pragma unroll
  for (int i = 0; i < 4; ++i)
#pragma unroll
    for (int r = 0; r < 4; ++r) {
      int lr = wr * 64 + (lane >> 4) * 4 + i * 16 + r;
      float S = rs[0][lr] + rs[1][lr] + rs[2][lr] + rs[3][lr];
      float SS = rss[0][lr] + rss[1][lr] + rss[2][lr] + rss[3][lr];
      float mean = S * (1.f / 512.f);
      float var = SS * (1.f / 512.f) - mean * mean;
      float rstd = rsqrtf(var + 1e-5f);
#pragma unroll
      for (int j = 0; j < 8; ++j) {
        float y = (acc[i][j][r] - mean) * rstd * gv[j] + b2v[j];
        acc[i][j][r] = siluf(y);
      }
    }

  if constexpr (!HEAD) {
#pragma unroll
    for (int i = 0; i < 4; ++i)
#pragma unroll
      for (int r = 0; r < 4; ++r) {
        int grow = row0 + wr * 64 + (lane >> 4) * 4 + i * 16 + r;
#pragma unroll
        for (int j = 0; j < 8; ++j)
          C[(size_t)grow * 512 + wc * 128 + (lane & 15) + j * 16] =
              __float2bfloat16(acc[i][j][r]);
      }
  } else {
#pragma unroll
    for (int r9 = 0; r9 < 9; ++r9) {
      float hw8[8];
#pragma unroll
      for (int j = 0; j < 8; ++j)
        hw8[j] = hw[r9 * 512 + wc * 128 + (lane & 15) + j * 16];
      float pacc[4][4];
#pragma unroll
      for (int i = 0; i < 4; ++i)
#pragma unroll
        for (int r = 0; r < 4; ++r) {
          float p = 0.f;
#pragma unroll
          for (int j = 0; j < 8; ++j) p = fmaf(acc[i][j][r], hw8[j], p);
#pragma unroll
          for (int off = 1; off < 16; off <<= 1) p += __shfl_xor(p, off, 64);
          pacc[i][r] = p;
        }
      if ((lane & 15) == 0) {
#pragma unroll
        for (int i = 0; i < 4; ++i)
#pragma unroll
          for (int r = 0; r < 4; ++r) {
            int lr = wr * 64 + (lane >> 4) * 4 + i * 16 + r;
            o9[wc][lr][r9] = pacc[i][r];
          }
      }
    }
    __syncthreads();
    if (tid < 128) {
      float raw[9];
#pragma unroll
      for (int r9 = 0; r9 < 9; ++r9)
        raw[r9] = o9[0][tid][r9] + o9[1][tid][r9] + o9[2][tid][r9] +
                  o9[3][tid][r9] + hb[r9];
      float* op = out + (size_t)(row0 + tid) * 9;
      op[0] = fmaxf(raw[0], 0.f) + log1pf(expf(-fabsf(raw[0])));
      op[1] = fmaxf(raw[1], 0.f) + log1pf(expf(-fabsf(raw[1])));
      op[2] = 1.f / (1.f + expf(-raw[2]));
      op[3] = 1.f / (1.f + expf(-raw[3]));
      op[4] = 1.f / (1.f + expf(-raw[4]));
      float mx = fmaxf(fmaxf(raw[5], raw[6]), fmaxf(raw[7], raw[8]));
      float e0 = expf(raw[5] - mx), e1 = expf(raw[6] - mx);
      float e2 = expf(raw[7] - mx), e3 = expf(raw[8] - mx);
      float inv = 1.f / (e0 + e1 + e2 + e3);
      op[5] = e0 * inv; op[6] = e1 * inv; op[7] = e2 * inv; op[8] = e3 * inv;
    }
  }
}

// ---------------------------------------------------------------- attn (MFMA)
// One block per (b,h,window-block): 4 waves x 32 queries. KV chunks of 64 keys,
// double-buffered with async-split staging; one barrier per chunk.
// Wave-uniform subtile skip: fully masked 32-key subtiles (exact zeros)
// contribute nothing and are skipped.
__global__ __launch_bounds__(256) void attn_kernel(
    const __hip_bfloat16* __restrict__ qkv, const float2* __restrict__ tab,
    __hip_bfloat16* __restrict__ o_out) {
  __shared__ __align__(16) short Kc[2][64 * 72];   // [key 64][dim 64 pad 72]
  __shared__ __align__(16) short Vt[2][64 * 72];   // [dim 64][key 64 pad 72]
  __shared__ __align__(16) float rbuf[4][32];
  const int blk = blockIdx.x;
  const int nbIdx = blk & 63;
  const int h = (blk >> 6) & 7;
  const int b = blk >> 9;
  const int tid = threadIdx.x;
  const int w = tid >> 6;
  const int lane = tid & 63;
  const int lq = lane & 31;
  const int hi = lane >> 5;
  const size_t seqBase = (size_t)b * LSEQ;
  const int qi = w * 32 + lq;
  const int qtok = nbIdx * 128 + qi;
  const int qmin = w * 32;

  const ushort* qkvu = (const ushort*)qkv;

  bf16x8 qf[4];
  {
    const ushort* Qrow = qkvu + (seqBase + qtok) * 1536 + h * 64;
#pragma unroll
    for (int s = 0; s < 4; ++s) {
      int dim0 = 16 * s + 8 * hi;
      bf16x8 qv = *(const bf16x8*)(Qrow + dim0);
      const float4* tp = (const float4*)(tab + qtok * 32 + dim0 / 2);
      float4 t01 = tp[0], t23 = tp[1];
      float cs[4] = {t01.x, t01.z, t23.x, t23.z};
      float sn[4] = {t01.y, t01.w, t23.y, t23.w};
      union { uint u[4]; bf16x8 v; } pk;
#pragma unroll
      for (int j = 0; j < 4; ++j) {
        float x1 = bf2f((ushort)qv[2 * j]);
        float x2 = bf2f((ushort)qv[2 * j + 1]);
        float r0 = (x1 * cs[j] - x2 * sn[j]) * 0.125f;
        float r1 = (x1 * sn[j] + x2 * cs[j]) * 0.125f;
        pk.u[j] = cvtpk_bf16(r0, r1);
      }
      qf[s] = pk.v;
    }
  }

  const f32x16 Z16 = {0.f};
  f32x16 oa0 = Z16, oa1 = Z16;
  float m0 = -3.0e38f, l = 0.f;

  const int cstart = (nbIdx == 0) ? 2 : 0;
  const int cw0 = (w >= 2) ? 1 : 0;
  const int cw1 = (w >= 2) ? 3 : 2;

  const int skk = tid >> 2;
  const int sd0 = (tid & 3) * 16;

  bf16x8 kreg0, kreg1, vreg0, vreg1;

  auto issue = [&](int c) {
    int ktok = (nbIdx - 1) * 128 + c * 64 + skk;
    const ushort* base = qkvu + (seqBase + ktok) * 1536 + h * 64 + sd0;
    kreg0 = *(const bf16x8*)(base + 512);
    kreg1 = *(const bf16x8*)(base + 512 + 8);
    vreg0 = *(const bf16x8*)(base + 1024);
    vreg1 = *(const bf16x8*)(base + 1024 + 8);
  };

  auto write_chunk = [&](int c) {
    short* Kb = Kc[c & 1];
    short* Vb = Vt[c & 1];
    int ktok = (nbIdx - 1) * 128 + c * 64 + skk;
    const float4* tp = (const float4*)(tab + ktok * 32 + (sd0 >> 1));
    float4 t0 = tp[0], t1 = tp[1], t2 = tp[2], t3 = tp[3];
    const int swk = ((skk >> 3) & 3) << 5;
    {
      float cs[4] = {t0.x, t0.z, t1.x, t1.z};
      float sn[4] = {t0.y, t0.w, t1.y, t1.w};
      union { uint u[4]; bf16x8 v; } pk;
#pragma unroll
      for (int j = 0; j < 4; ++j) {
        float x1 = bf2f((ushort)kreg0[2 * j]);
        float x2 = bf2f((ushort)kreg0[2 * j + 1]);
        pk.u[j] = cvtpk_bf16(x1 * cs[j] - x2 * sn[j], x1 * sn[j] + x2 * cs[j]);
      }
      *(bf16x8*)((char*)Kb + skk * 144 + ((sd0 * 2) ^ swk)) = pk.v;
    }
    {
      float cs[4] = {t2.x, t2.z, t3.x, t3.z};
      float sn[4] = {t2.y, t2.w, t3.y, t3.w};
      union { uint u[4]; bf16x8 v; } pk;
#pragma unroll
      for (int j = 0; j < 4; ++j) {
        float x1 = bf2f((ushort)kreg1[2 * j]);
        float x2 = bf2f((ushort)kreg1[2 * j + 1]);
        pk.u[j] = cvtpk_bf16(x1 * cs[j] - x2 * sn[j], x1 * sn[j] + x2 * cs[j]);
      }
      *(bf16x8*)((char*)Kb + skk * 144 + (((sd0 + 8) * 2) ^ swk)) = pk.v;
    }
#pragma unroll
    for (int j = 0; j < 8; ++j) {
      int d0 = sd0 + j;
      *(short*)((char*)Vb + d0 * 144 +
                ((skk * 2) ^ (((d0 >> 4) & 3) << 5))) = vreg0[j];
      int d1 = sd0 + 8 + j;
      *(short*)((char*)Vb + d1 * 144 +
                ((skk * 2) ^ (((d1 >> 4) & 3) << 5))) = vreg1[j];
    }
  };

  issue(cstart);
  write_chunk(cstart);

  for (int c = cstart; c < 4; ++c) {
    if (c < 3) issue(c + 1);
    __syncthreads();
    if (c >= cw0 && c <= cw1) {
      const char* Kb = (const char*)Kc[c & 1];
      const char* Vb = (const char*)Vt[c & 1];

      // wave-uniform subtile validity: keys [ks, ks+31] vs [qmin, qmin+159]
      bool val[2];
#pragma unroll
      for (int t2 = 0; t2 < 2; ++t2) {
        int ks = c * 64 + 32 * t2;
        val[t2] = (ks + 31 >= qmin) && (ks <= qmin + 159);
      }

      float p2[2][16];
      float pmax = -3.0e38f;
#pragma unroll
      for (int t2 = 0; t2 < 2; ++t2) {
        if (!val[t2]) continue;
        bf16x8 ka[4];
#pragma unroll
        for (int s = 0; s < 4; ++s) {
          int kk = 32 * t2 + lq;
          int byteoff =
              kk * 144 + ((32 * s + 16 * hi) ^ (((kk >> 3) & 3) << 5));
          ka[s] = *(const bf16x8*)(Kb + byteoff);
        }
        f32x16 st = Z16;
#pragma unroll
        for (int s = 0; s < 4; ++s)
          st = __builtin_amdgcn_mfma_f32_32x32x16_bf16(ka[s], qf[s], st, 0, 0, 0);
#pragma unroll
        for (int r = 0; r < 16; ++r) {
          int key = c * 64 + 32 * t2 + (r & 3) + 8 * (r >> 2) + 4 * hi;
          float sv = st[r];
          bool act = (key >= qi) && (key <= qi + 128);
          sv = act ? sv : -1.0e30f;
          p2[t2][r] = sv;
          pmax = fmaxf(pmax, sv);
        }
      }
      pmax = fmaxf(pmax, __shfl_xor(pmax, 32));
      if (__any(pmax > m0 + 8.f)) {
        float nm = fmaxf(m0, pmax);
        float rr2 = __expf(m0 - nm);
        l *= rr2;
        m0 = nm;
        rbuf[w][lq] = rr2;
        asm volatile("s_waitcnt lgkmcnt(0)" ::: "memory");
#pragma unroll
        for (int a = 0; a < 4; ++a) {
          f32x4 r4 = *(const f32x4*)&rbuf[w][8 * a + 4 * hi];
#pragma unroll
          for (int j = 0; j < 4; ++j) {
            oa0[4 * a + j] *= r4[j];
            oa1[4 * a + j] *= r4[j];
          }
        }
      }
      float lsum = 0.f;
#pragma unroll
      for (int t2 = 0; t2 < 2; ++t2) {
        if (!val[t2]) continue;
#pragma unroll
        for (int r = 0; r < 16; ++r) {
          float p = __expf(p2[t2][r] - m0);
          p2[t2][r] = p;
          lsum += p;
        }
      }
      l += lsum + __shfl_xor(lsum, 32);

#pragma unroll
      for (int t2 = 0; t2 < 2; ++t2) {
        if (!val[t2]) continue;
        union { uint u[4]; bf16x8 v; } pa[2];
#pragma unroll
        for (int sl = 0; sl < 2; ++sl) {
          const float* pp = &p2[t2][8 * sl];
          uint a0 = cvtpk_bf16(pp[0], pp[1]);
          uint a1 = cvtpk_bf16(pp[2], pp[3]);
          uint b0 = cvtpk_bf16(pp[4], pp[5]);
          uint b1 = cvtpk_bf16(pp[6], pp[7]);
          perm32swap(a0, b0);
          perm32swap(a1, b1);
          pa[sl].u[0] = a0; pa[sl].u[1] = a1;
          pa[sl].u[2] = b0; pa[sl].u[3] = b1;
        }
#pragma unroll
        for (int sl = 0; sl < 2; ++sl) {
          int slot = 2 * t2 + sl;
          {
            int d = lq;
            int byteoff =
                d * 144 + ((32 * slot + 16 * hi) ^ (((d >> 4) & 3) << 5));
            bf16x8 vb = *(const bf16x8*)(Vb + byteoff);
            oa0 = __builtin_amdgcn_mfma_f32_32x32x16_bf16(pa[sl].v, vb, oa0, 0, 0, 0);
          }
          {
            int d = 32 + lq;
            int byteoff =
                d * 144 + ((32 * slot + 16 * hi) ^ (((d >> 4) & 3) << 5));
            bf16x8 vb = *(const bf16x8*)(Vb + byteoff);
            oa1 = __builtin_amdgcn_mfma_f32_32x32x16_bf16(pa[sl].v, vb, oa1, 0, 0, 0);
          }
        }
      }
    }
    if (c < 3) write_chunk(c + 1);
  }

  rbuf[w][lq] = 1.f / l;
  asm volatile("s_waitcnt lgkmcnt(0)" ::: "memory");
  const int q0 = nbIdx * 128 + 32 * w;
#pragma unroll
  for (int a = 0; a < 4; ++a) {
    f32x4 r4 = *(const f32x4*)&rbuf[w][8 * a + 4 * hi];
#pragma unroll
    for (int j = 0; j < 4; ++j) {
      int tok = q0 + 8 * a + 4 * hi + j;
      __hip_bfloat16* orow = o_out + (seqBase + tok) * 512 + h * 64;
      orow[lq] = __float2bfloat16(oa0[4 * a + j] * r4[j]);
      orow[32 + lq] = __float2bfloat16(oa1[4 * a + j] * r4[j]);
    }
  }
}

// ---------------------------------------------------------------- launch
// Workspace layout (~133 MB peak):
//   w16: bf16 [inst | outp | qkv(permuted) | wcat] ; rope table (2MB)
//   R1 (96MB): {cat M*576 | Fb M*192} -> qkvb M*1536
//   R2 (32MB): hb bf16 -> att bf16
extern "C" void kernel_launch(void* const* d_in, const int* in_sizes, int n_in,
                              void* d_out, int out_size, void* d_ws,
                              size_t ws_size, hipStream_t stream) {
  const float* emb = (const float*)d_in[0];
  const float* reg_w = (const float*)d_in[1];
  const float* reg_b = (const float*)d_in[2];
  const float* br_w = (const float*)d_in[3];
  const float* br_b = (const float*)d_in[4];
  const float* mem_w = (const float*)d_in[5];
  const float* mem_b = (const float*)d_in[6];
  const float* inst_w = (const float*)d_in[7];
  const float* inst_b = (const float*)d_in[8];
  const float* ln1_g = (const float*)d_in[9];
  const float* ln1_b = (const float*)d_in[10];
  const float* qkv_w = (const float*)d_in[11];
  const float* outp_w = (const float*)d_in[12];
  const float* outp_b = (const float*)d_in[13];
  const float* ln2_g = (const float*)d_in[14];
  const float* ln2_b = (const float*)d_in[15];
  const float* head_w = (const float*)d_in[16];
  const float* head_b = (const float*)d_in[17];
  const int* x = (const int*)d_in[18];
  float* out = (float*)d_out;

  const int M = M_TOK;
  char* wsb = (char*)d_ws;
  __hip_bfloat16* w16 = (__hip_bfloat16*)wsb;
  __hip_bfloat16* w1 = w16;                        // inst
  __hip_bfloat16* w3 = w16 + NW1;                  // outp
  __hip_bfloat16* w2 = w16 + NW1 + NW3;            // qkv (permuted)
  __hip_bfloat16* wcat = w16 + NW1 + NW3 + NW2;    // feature proj
  size_t woff = ((size_t)(NW1 + NW2 + NW3 + NW4) * 2 + 255) & ~(size_t)255;
  float2* tab = (float2*)(wsb + woff);             // 2MB
  size_t toff = woff + (size_t)NTAB * 8;
  char* r1 = wsb + toff;                           // 96 MB region
  char* r2 = r1 + (size_t)M * 1536 * 2;            // 32 MB region
  __hip_bfloat16* cat = (__hip_bfloat16*)r1;       // M*576
  __hip_bfloat16* Fb = (__hip_bfloat16*)(r1 + (size_t)M * 576 * 2);  // M*192
  __hip_bfloat16* qkvb = (__hip_bfloat16*)r1;      // M*1536
  __hip_bfloat16* hb = (__hip_bfloat16*)r2;        // M*512
  __hip_bfloat16* att = (__hip_bfloat16*)r2;       // M*512

  // 0. all weight conversion + rope table (one kernel)
  const int setup_tot = NW1 + NW3 + NW2 + NW4 + NTAB;
  setup_kernel<<<(setup_tot + 255) / 256, 256, 0, stream>>>(
      inst_w, outp_w, qkv_w, reg_w, reg_b, br_w, br_b, mem_w, mem_b, w16, tab);
  // 1. prep: cat[:,0:192] = silu(emb[tid]) ; Fb = [1, feats, 0]
  prep_kernel<<<(M * 48) / 256, 256, 0, stream>>>(x, emb, cat, Fb);
  // 1b. feature proj: cat[:,192:576] = silu(Fb @ wcat^T)
  gemm_mfma<__hip_bfloat16, true><<<(M / 128) * 3, 256, 0, stream>>>(
      (const ushort*)Fb, (const ushort*)wcat, nullptr, cat + 192, M, 384, 192,
      576, 3);
  // 2. inst proj + LN1 + silu fused: hb = silu(LN(cat @ w1^T + b))
  gemm_ln_fused<false><<<M / 128, 512, 0, stream>>>(
      (const ushort*)cat, (const ushort*)w1, inst_b, ln1_g, ln1_b, nullptr,
      nullptr, hb, nullptr, 576);
  // 3. qkv proj (permuted cols): hb @ w2^T -> qkvb planes [Q|K|V]
  gemm_mfma<__hip_bfloat16, false><<<(M / 128) * 12, 256, 0, stream>>>(
      (const ushort*)hb, (const ushort*)w2, nullptr, qkvb, M, 1536, 512, 1536,
      12);
  // 4. attention (MFMA) -> att (bf16, [M][512] heads concatenated)
  attn_kernel<<<BATCH * 8 * 64, 256, 0, stream>>>(qkvb, tab, att);
  // 5. outp proj + LN2 + silu + head + activations fused -> out
  gemm_ln_fused<true><<<M / 128, 512, 0, stream>>>(
      (const ushort*)att, (const ushort*)w3, outp_b, ln2_g, ln2_b, head_w,
      head_b, nullptr, out, 512);
}